// Round 11
// baseline (515.174 us; speedup 1.0000x reference)
//
#include <hip/hip_runtime.h>
#include <math.h>

#define B_ 8192
#define D_ 4096
#define K_ 64
#define EPSF 1e-8f
#define LN2F 0.69314718056f
#define ENT_GRID 2048
#define CT_ 16  // col tiles of 256 floats
#define RS_ 32  // row splits of 256 rows

typedef float f32x4 __attribute__((ext_vector_type(4)));

// ---------------- kernels ----------------

// one wave per row; K_ == 64 == wavefront: one coalesced read + ballot
__global__ void k_labels(const float* __restrict__ probs, int* __restrict__ labels) {
  int row = blockIdx.x * 4 + (threadIdx.x >> 6);
  int lane = threadIdx.x & 63;
  float p = probs[(size_t)row * K_ + lane];
  unsigned long long m = __ballot(p > 0.5f);
  if (lane == 0) {
    int k = __ffsll(m) - 1;
    labels[row] = (k >= 0) ? k : 0;
  }
}

// block per row, sequential rows: w = 1/max(||a||,eps), diag = s*w*w (proven 6.4 TB/s)
__global__ __launch_bounds__(256) void k_norms(const float* __restrict__ acts,
                                               float* __restrict__ wout,
                                               float* __restrict__ diagout) {
  __shared__ float lds[4];
  int row = blockIdx.x;
  const f32x4* rp = (const f32x4*)(acts + (size_t)row * D_);
  int t = threadIdx.x;
  f32x4 v0 = rp[t];
  f32x4 v1 = rp[t + 256];
  f32x4 v2 = rp[t + 512];
  f32x4 v3 = rp[t + 768];
  float s = v0.x * v0.x + v0.y * v0.y + v0.z * v0.z + v0.w * v0.w;
  s += v1.x * v1.x + v1.y * v1.y + v1.z * v1.z + v1.w * v1.w;
  s += v2.x * v2.x + v2.y * v2.y + v2.z * v2.z + v2.w * v2.w;
  s += v3.x * v3.x + v3.y * v3.y + v3.z * v3.z + v3.w * v3.w;
#pragma unroll
  for (int o = 32; o > 0; o >>= 1) s += __shfl_down(s, o);
  if ((t & 63) == 0) lds[t >> 6] = s;
  __syncthreads();
  if (t == 0) {
    s = lds[0] + lds[1] + lds[2] + lds[3];
    float w = 1.0f / fmaxf(sqrtf(s), EPSF);
    wout[row] = w;
    diagout[row] = s * w * w;
  }
}

// Staged-LDS class-sum scatter. Block = (col-tile 256, 256 sequential rows).
// Stage phase: 2x f32x4 coalesced loads -> LDS (loads forced parallel, ONE
// memory latency per 8 rows). Consume phase: pure LDS — broadcast read +
// ds_add_f32 into thread-private column C[k][tid] (no contention, no global
// round trips). Reads are sequential tiles of L3-resident data (runs right
// after k_norms streamed this tensor).
__global__ __launch_bounds__(256) void k_scatter(const float* __restrict__ acts,
                                                 const int* __restrict__ labels,
                                                 const float* __restrict__ warr,
                                                 float* __restrict__ Cpart) {
  __shared__ float C[K_][256];  // 64KB, thread-private columns
  __shared__ float S[8][256];   // 8KB stage
  __shared__ float WL[256];
  __shared__ int LB[256];
  int tid = threadIdx.x;
  int tile = blockIdx.x & (CT_ - 1);
  int split = blockIdx.x >> 4;  // CT_ == 16
  int rbase = split * 256;

  LB[tid] = labels[rbase + tid];
  WL[tid] = warr[rbase + tid];
#pragma unroll
  for (int k = 0; k < K_; ++k) C[k][tid] = 0.f;

  const f32x4* A = (const f32x4*)acts;
  int colv = tid & 63;
  int rl0 = tid >> 6;  // 0..3
  __syncthreads();     // LB/WL visible

  for (int it = 0; it < 256; it += 8) {
    f32x4 v0 = A[(size_t)(rbase + it + rl0) * (D_ / 4) + tile * 64 + colv];
    f32x4 v1 = A[(size_t)(rbase + it + 4 + rl0) * (D_ / 4) + tile * 64 + colv];
    ((f32x4*)S)[tid] = v0;
    ((f32x4*)S)[tid + 256] = v1;
    __syncthreads();
#pragma unroll
    for (int j = 0; j < 8; ++j) {
      int r = it + j;
      atomicAdd(&C[LB[r]][tid], WL[r] * S[j][tid]);
    }
    __syncthreads();
  }

  // writeback own column: Cpart[split][k][tile*256+tid]
  float* cp = Cpart + (size_t)split * K_ * D_ + tile * 256 + tid;
#pragma unroll
  for (int k = 0; k < K_; ++k) cp[(size_t)k * D_] = C[k][tid];
}

// mSm partials: 512 blocks; b<256 -> tensor1, else tensor8. k=b>>2, quarter q=b&3.
__global__ __launch_bounds__(256) void k_msm(const float* __restrict__ Cpart1,
                                             const float* __restrict__ Cpart8,
                                             float* __restrict__ msp1,
                                             float* __restrict__ msp8) {
  __shared__ float lds[4];
  int b = blockIdx.x;
  const float* Cpart = (b < 256) ? Cpart1 : Cpart8;
  float* msp = (b < 256) ? msp1 : msp8;
  b &= 255;
  int k = b >> 2;
  int q = b & 3;
  int t = threadIdx.x;
  int col = q * 1024 + 4 * t;
  f32x4 c = 0.f;
  for (int s = 0; s < RS_; ++s)
    c += *(const f32x4*)(Cpart + ((size_t)s * K_ + k) * D_ + col);
  float sq = c.x * c.x + c.y * c.y + c.z * c.z + c.w * c.w;
#pragma unroll
  for (int o = 32; o > 0; o >>= 1) sq += __shfl_down(sq, o);
  if ((t & 63) == 0) lds[t >> 6] = sq;
  __syncthreads();
  if (t == 0) msp[blockIdx.x & 255] = lds[0] + lds[1] + lds[2] + lds[3];
}

__device__ __forceinline__ float ent1(float p) {
  p = fminf(fmaxf(p, EPSF), 1.0f - EPSF);
  float q = 1.0f - p;
  float lp = __builtin_amdgcn_logf(p);  // v_log_f32: log2
  float lq = __builtin_amdgcn_logf(fmaxf(q, 1e-38f));
  return -(p * lp + q * lq);
}

__device__ __forceinline__ float ent4(f32x4 v) {
  return ent1(v.x) + ent1(v.y) + ent1(v.z) + ent1(v.w);
}

// binary entropy over both masks; plain loads, 16 in flight (proven shape)
__global__ __launch_bounds__(256) void k_entropy(const f32x4* __restrict__ m1,
                                                 const f32x4* __restrict__ m8,
                                                 double* __restrict__ entpart) {
  __shared__ float lds[8];
  const int CHUNK = (B_ * D_ / 4) / ENT_GRID;  // 4096 f32x4 per block per mask
  int base = blockIdx.x * CHUNK;
  int t = threadIdx.x;
  float s1 = 0.f, s8 = 0.f;
#pragma unroll
  for (int o = 0; o < 2; ++o) {
    f32x4 a[8], b[8];
#pragma unroll
    for (int j = 0; j < 8; ++j) {
      int idx = base + t + (o * 8 + j) * 256;
      a[j] = m1[idx];
      b[j] = m8[idx];
    }
#pragma unroll
    for (int j = 0; j < 8; ++j) {
      s1 += ent4(a[j]);
      s8 += ent4(b[j]);
    }
  }
#pragma unroll
  for (int o = 32; o > 0; o >>= 1) {
    s1 += __shfl_down(s1, o);
    s8 += __shfl_down(s8, o);
  }
  int wid = t >> 6;
  if ((t & 63) == 0) { lds[wid] = s1; lds[4 + wid] = s8; }
  __syncthreads();
  if (t == 0) {
    float t1 = lds[0] + lds[1] + lds[2] + lds[3];
    float t8 = lds[4] + lds[5] + lds[6] + lds[7];
    entpart[blockIdx.x]            = (double)(t1 * LN2F);
    entpart[ENT_GRID + blockIdx.x] = (double)(t8 * LN2F);
  }
}

__global__ void k_final(const double* __restrict__ entpart, const int* __restrict__ labels,
                        const float* __restrict__ diag1, const float* __restrict__ diag8,
                        const float* __restrict__ msp1, const float* __restrict__ msp8,
                        float* __restrict__ out) {
  __shared__ float sd1[K_], sd8[K_];
  __shared__ int cnt[K_];
  __shared__ double dl[8];
  int t = threadIdx.x;
  if (t < K_) { sd1[t] = 0.f; sd8[t] = 0.f; cnt[t] = 0; }
  __syncthreads();
  for (int r = t; r < B_; r += 256) {
    int lb = labels[r];
    atomicAdd(&sd1[lb], diag1[r]);
    atomicAdd(&sd8[lb], diag8[r]);
    atomicAdd(&cnt[lb], 1);
  }
  double e1 = 0.0, e8 = 0.0;
  for (int i = t; i < ENT_GRID; i += 256) {
    e1 += entpart[i];
    e8 += entpart[ENT_GRID + i];
  }
#pragma unroll
  for (int o = 32; o > 0; o >>= 1) {
    e1 += __shfl_down(e1, o);
    e8 += __shfl_down(e8, o);
  }
  int wid = t >> 6;
  if ((t & 63) == 0) { dl[wid] = e1; dl[4 + wid] = e8; }
  __syncthreads();  // covers sd/cnt atomics and dl stores
  float pcm1 = 0.f, pcm8 = 0.f, valid = 0.f;
  if (t < K_) {
    float mSm1 = msp1[t * 4] + msp1[t * 4 + 1] + msp1[t * 4 + 2] + msp1[t * 4 + 3];
    float mSm8 = msp8[t * 4] + msp8[t * 4 + 1] + msp8[t * 4 + 2] + msp8[t * 4 + 3];
    float n = (float)cnt[t];
    bool v = (n >= 2.0f);
    float np = fmaxf(0.5f * n * (n - 1.0f), 1.0f);
    valid = v ? 1.0f : 0.f;
    pcm1 = v ? 0.5f * (mSm1 - sd1[t]) / np : 0.f;
    pcm8 = v ? 0.5f * (mSm8 - sd8[t]) / np : 0.f;
  }
#pragma unroll
  for (int o = 32; o > 0; o >>= 1) {
    pcm1 += __shfl_down(pcm1, o);
    pcm8 += __shfl_down(pcm8, o);
    valid += __shfl_down(valid, o);
  }
  if (t == 0) {
    double etot1 = dl[0] + dl[1] + dl[2] + dl[3];
    double etot8 = dl[4] + dl[5] + dl[6] + dl[7];
    float sp1 = (float)(etot1 / (double)((long long)B_ * D_));
    float sp8 = (float)(etot8 / (double)((long long)B_ * D_));
    float cs1 = (valid > 0.f) ? pcm1 / fmaxf(valid, 1.0f) : 0.f;
    float cs8 = (valid > 0.f) ? pcm8 / fmaxf(valid, 1.0f) : 0.f;
    float sim1 = -cs1, sim8 = -cs8;
    out[0] = sim1 + sim8 + 0.001f * (sp1 + sp8);
    out[1] = sim1;
    out[2] = sim8;
    out[3] = sp1;
    out[4] = sp8;
  }
}

// ---------------- launcher ----------------
// ws layout (bytes):
//   0        : double entpart[2][2048]   32768
//   32768    : int    labels[B]          32768
//   65536    : float  msp1[256]          1024
//   66560    : float  msp8[256]          1024
//   67584    : float  w1[B]              32768
//   100352   : float  diag1[B]           32768
//   133120   : float  w8[B]              32768
//   165888   : float  diag8[B]           32768
//   198656   : float  Cpart1[32][K][D]   33554432
//   33753088 : float  Cpart8[32][K][D]   33554432
//   total ~67 MB (ws_size observed ~539 MB)

extern "C" void kernel_launch(void* const* d_in, const int* in_sizes, int n_in,
                              void* d_out, int out_size, void* d_ws, size_t ws_size,
                              hipStream_t stream) {
  const float* probs = (const float*)d_in[0];
  const float* a1 = (const float*)d_in[1];
  const float* a8 = (const float*)d_in[2];
  const float* m1 = (const float*)d_in[3];
  const float* m8 = (const float*)d_in[4];
  float* out = (float*)d_out;
  char* ws = (char*)d_ws;

  double* entpart = (double*)(ws + 0);
  int* labels = (int*)(ws + 32768);
  float* msp1 = (float*)(ws + 65536);
  float* msp8 = (float*)(ws + 66560);
  float* w1 = (float*)(ws + 67584);
  float* diag1 = (float*)(ws + 100352);
  float* w8 = (float*)(ws + 133120);
  float* diag8 = (float*)(ws + 165888);
  float* Cpart1 = (float*)(ws + 198656);
  float* Cpart8 = (float*)(ws + 33753088);

  k_labels<<<B_ / 4, 256, 0, stream>>>(probs, labels);
  // per-tensor pairing: scatter re-reads the tensor k_norms just pulled into L3
  k_norms<<<B_, 256, 0, stream>>>(a1, w1, diag1);
  k_scatter<<<CT_ * RS_, 256, 0, stream>>>(a1, labels, w1, Cpart1);
  k_norms<<<B_, 256, 0, stream>>>(a8, w8, diag8);
  k_scatter<<<CT_ * RS_, 256, 0, stream>>>(a8, labels, w8, Cpart8);
  // masks last: don't disturb acts L3 residency
  k_entropy<<<ENT_GRID, 256, 0, stream>>>((const f32x4*)m1, (const f32x4*)m8, entpart);
  k_msm<<<512, 256, 0, stream>>>(Cpart1, Cpart8, msp1, msp8);
  k_final<<<1, 256, 0, stream>>>(entpart, labels, diag1, diag8, msp1, msp8, out);
}

// Round 12
// 314.076 us; speedup vs baseline: 1.6403x; 1.6403x over previous
//
#include <hip/hip_runtime.h>
#include <math.h>

#define B_ 8192
#define D_ 4096
#define K_ 64
#define EPSF 1e-8f
#define LN2F 0.69314718056f
#define ENT_GRID 2048
#define CT_ 16                // col tiles of 256 floats
#define RS_ 16                // row splits
#define ROWS_ (B_ / RS_)      // 512 rows per block

typedef float f32x4 __attribute__((ext_vector_type(4)));

// ---------------- kernels ----------------

// zero counts[64] + sd1[64] + sd8[64] (contiguous 192 words)
__global__ void k_init(int* __restrict__ z) {
  if (threadIdx.x < 192) z[threadIdx.x] = 0;
}

// one wave per row; K_ == 64 == wavefront: one coalesced read + ballot
__global__ void k_labels(const float* __restrict__ probs, int* __restrict__ labels,
                         int* __restrict__ counts) {
  int row = blockIdx.x * 4 + (threadIdx.x >> 6);
  int lane = threadIdx.x & 63;
  float p = probs[(size_t)row * K_ + lane];
  unsigned long long m = __ballot(p > 0.5f);
  if (lane == 0) {
    int k = __ffsll(m) - 1;
    labels[row] = (k >= 0) ? k : 0;
    if (k >= 0) atomicAdd(&counts[k], 1);
  }
}

// block per row, sequential: w = 1/max(||a||,eps); ONE global atomic per block
// into sd[class] (r1/r3-proven ~6.4 TB/s shape).
__global__ __launch_bounds__(256) void k_norms(const float* __restrict__ acts,
                                               const int* __restrict__ labels,
                                               float* __restrict__ wout,
                                               float* __restrict__ sd) {
  __shared__ float lds[4];
  int row = blockIdx.x;
  const f32x4* rp = (const f32x4*)(acts + (size_t)row * D_);
  int t = threadIdx.x;
  f32x4 v0 = rp[t];
  f32x4 v1 = rp[t + 256];
  f32x4 v2 = rp[t + 512];
  f32x4 v3 = rp[t + 768];
  float s = v0.x * v0.x + v0.y * v0.y + v0.z * v0.z + v0.w * v0.w;
  s += v1.x * v1.x + v1.y * v1.y + v1.z * v1.z + v1.w * v1.w;
  s += v2.x * v2.x + v2.y * v2.y + v2.z * v2.z + v2.w * v2.w;
  s += v3.x * v3.x + v3.y * v3.y + v3.z * v3.z + v3.w * v3.w;
#pragma unroll
  for (int o = 32; o > 0; o >>= 1) s += __shfl_down(s, o);
  if ((t & 63) == 0) lds[t >> 6] = s;
  __syncthreads();
  if (t == 0) {
    s = lds[0] + lds[1] + lds[2] + lds[3];
    float w = 1.0f / fmaxf(sqrtf(s), EPSF);
    wout[row] = w;
    atomicAdd(&sd[labels[row]], s * w * w);
  }
}

#define SC_LOAD(V, IT)                                                       \
  {                                                                          \
    const float* ap_ = ap + (size_t)(IT)*D_;                                 \
    _Pragma("unroll") for (int j = 0; j < 8; ++j) V[j] = ap_[(size_t)j * D_];\
  }

#define SC_CONSUME(V, IT)                                                    \
  {                                                                          \
    _Pragma("unroll") for (int j = 0; j < 8; ++j) {                          \
      int lb_ = lp[(IT) + j];                                                \
      float w_ = wp[(IT) + j];                                               \
      C[lb_][tid] += w_ * V[j];                                              \
    }                                                                        \
  }

// Class-sum scatter, NO atomics, NO barriers: thread tid exclusively owns LDS
// column C[*][tid] -> plain read-modify-write is race-free. Sequential
// coalesced reads (wave = 256B burst per row), 8-row double-buffered register
// prefetch keeps 2KB/wave in flight. Block = (col-tile of 256, 512 seq rows).
__global__ __launch_bounds__(256) void k_scatter(const float* __restrict__ acts,
                                                 const int* __restrict__ labels,
                                                 const float* __restrict__ warr,
                                                 float* __restrict__ Cpart) {
  __shared__ float C[K_][256];  // 64KB, thread-private columns
  int tid = threadIdx.x;
  int tile = blockIdx.x & (CT_ - 1);
  int split = blockIdx.x >> 4;  // CT_ == 16
  int rbase = split * ROWS_;

#pragma unroll
  for (int k = 0; k < K_; ++k) C[k][tid] = 0.f;

  const float* ap = acts + (size_t)rbase * D_ + tile * 256 + tid;
  const int* lp = labels + rbase;
  const float* wp = warr + rbase;

  float va[8], vb[8];
  SC_LOAD(va, 0);
  for (int it = 0; it < ROWS_; it += 16) {
    SC_LOAD(vb, it + 8);
    SC_CONSUME(va, it);
    if (it + 16 < ROWS_) SC_LOAD(va, it + 16);
    SC_CONSUME(vb, it + 8);
  }

  // writeback own column: Cpart[split][k][tile*256+tid] (1KB/wave per k)
  float* cp = Cpart + (size_t)split * (K_ * D_) + tile * 256 + tid;
#pragma unroll
  for (int k = 0; k < K_; ++k) cp[(size_t)k * D_] = C[k][tid];
}

// mSm partials: 512 blocks; b<256 -> tensor1, else tensor8. k=b>>2, quarter q=b&3.
__global__ __launch_bounds__(256) void k_msm(const float* __restrict__ Cpart1,
                                             const float* __restrict__ Cpart8,
                                             float* __restrict__ msp1,
                                             float* __restrict__ msp8) {
  __shared__ float lds[4];
  int b = blockIdx.x;
  const float* Cpart = (b < 256) ? Cpart1 : Cpart8;
  float* msp = (b < 256) ? msp1 : msp8;
  b &= 255;
  int k = b >> 2;
  int q = b & 3;
  int t = threadIdx.x;
  int col = q * 1024 + 4 * t;
  f32x4 c = 0.f;
#pragma unroll
  for (int s = 0; s < RS_; ++s)
    c += *(const f32x4*)(Cpart + ((size_t)s * K_ + k) * D_ + col);
  float sq = c.x * c.x + c.y * c.y + c.z * c.z + c.w * c.w;
#pragma unroll
  for (int o = 32; o > 0; o >>= 1) sq += __shfl_down(sq, o);
  if ((t & 63) == 0) lds[t >> 6] = sq;
  __syncthreads();
  if (t == 0) msp[blockIdx.x & 255] = lds[0] + lds[1] + lds[2] + lds[3];
}

__device__ __forceinline__ float ent1(float p) {
  p = fminf(fmaxf(p, EPSF), 1.0f - EPSF);
  float q = 1.0f - p;
  float lp = __builtin_amdgcn_logf(p);  // v_log_f32: log2
  float lq = __builtin_amdgcn_logf(fmaxf(q, 1e-38f));
  return -(p * lp + q * lq);
}

__device__ __forceinline__ float ent4(f32x4 v) {
  return ent1(v.x) + ent1(v.y) + ent1(v.z) + ent1(v.w);
}

// binary entropy over both masks; plain loads, 16 in flight (r8-proven ~50us)
__global__ __launch_bounds__(256) void k_entropy(const f32x4* __restrict__ m1,
                                                 const f32x4* __restrict__ m8,
                                                 double* __restrict__ entpart) {
  __shared__ float lds[8];
  const int CHUNK = (B_ * D_ / 4) / ENT_GRID;  // 4096 f32x4 per block per mask
  int base = blockIdx.x * CHUNK;
  int t = threadIdx.x;
  float s1 = 0.f, s8 = 0.f;
#pragma unroll
  for (int o = 0; o < 2; ++o) {
    f32x4 a[8], b[8];
#pragma unroll
    for (int j = 0; j < 8; ++j) {
      int idx = base + t + (o * 8 + j) * 256;
      a[j] = m1[idx];
      b[j] = m8[idx];
    }
#pragma unroll
    for (int j = 0; j < 8; ++j) {
      s1 += ent4(a[j]);
      s8 += ent4(b[j]);
    }
  }
#pragma unroll
  for (int o = 32; o > 0; o >>= 1) {
    s1 += __shfl_down(s1, o);
    s8 += __shfl_down(s8, o);
  }
  int wid = t >> 6;
  if ((t & 63) == 0) { lds[wid] = s1; lds[4 + wid] = s8; }
  __syncthreads();
  if (t == 0) {
    float t1 = lds[0] + lds[1] + lds[2] + lds[3];
    float t8 = lds[4] + lds[5] + lds[6] + lds[7];
    entpart[blockIdx.x]            = (double)(t1 * LN2F);
    entpart[ENT_GRID + blockIdx.x] = (double)(t8 * LN2F);
  }
}

// no LDS atomics: sd/counts precomputed by k_norms/k_labels
__global__ void k_final(const double* __restrict__ entpart, const int* __restrict__ counts,
                        const float* __restrict__ sd1, const float* __restrict__ sd8,
                        const float* __restrict__ msp1, const float* __restrict__ msp8,
                        float* __restrict__ out) {
  __shared__ double dl[8];
  int t = threadIdx.x;
  double e1 = 0.0, e8 = 0.0;
  for (int i = t; i < ENT_GRID; i += 256) {
    e1 += entpart[i];
    e8 += entpart[ENT_GRID + i];
  }
#pragma unroll
  for (int o = 32; o > 0; o >>= 1) {
    e1 += __shfl_down(e1, o);
    e8 += __shfl_down(e8, o);
  }
  int wid = t >> 6;
  if ((t & 63) == 0) { dl[wid] = e1; dl[4 + wid] = e8; }
  __syncthreads();
  float pcm1 = 0.f, pcm8 = 0.f, valid = 0.f;
  if (t < K_) {
    float mSm1 = msp1[t * 4] + msp1[t * 4 + 1] + msp1[t * 4 + 2] + msp1[t * 4 + 3];
    float mSm8 = msp8[t * 4] + msp8[t * 4 + 1] + msp8[t * 4 + 2] + msp8[t * 4 + 3];
    float n = (float)counts[t];
    bool v = (n >= 2.0f);
    float np = fmaxf(0.5f * n * (n - 1.0f), 1.0f);
    valid = v ? 1.0f : 0.f;
    pcm1 = v ? 0.5f * (mSm1 - sd1[t]) / np : 0.f;
    pcm8 = v ? 0.5f * (mSm8 - sd8[t]) / np : 0.f;
  }
#pragma unroll
  for (int o = 32; o > 0; o >>= 1) {
    pcm1 += __shfl_down(pcm1, o);
    pcm8 += __shfl_down(pcm8, o);
    valid += __shfl_down(valid, o);
  }
  if (t == 0) {
    double etot1 = dl[0] + dl[1] + dl[2] + dl[3];
    double etot8 = dl[4] + dl[5] + dl[6] + dl[7];
    float sp1 = (float)(etot1 / (double)((long long)B_ * D_));
    float sp8 = (float)(etot8 / (double)((long long)B_ * D_));
    float cs1 = (valid > 0.f) ? pcm1 / fmaxf(valid, 1.0f) : 0.f;
    float cs8 = (valid > 0.f) ? pcm8 / fmaxf(valid, 1.0f) : 0.f;
    float sim1 = -cs1, sim8 = -cs8;
    out[0] = sim1 + sim8 + 0.001f * (sp1 + sp8);
    out[1] = sim1;
    out[2] = sim8;
    out[3] = sp1;
    out[4] = sp8;
  }
}

// ---------------- launcher ----------------
// ws layout (bytes):
//   0        : double entpart[2][2048]   32768
//   32768    : int    labels[B]          32768
//   65536    : int    counts[64]         256  \
//   65792    : float  sd1[64]            256   } zeroed together (192 words)
//   66048    : float  sd8[64]            256  /
//   66304    : float  msp1[256]          1024
//   67328    : float  msp8[256]          1024
//   69632    : float  w1[B]              32768
//   102400   : float  w8[B]              32768
//   135168   : float  Cpart1[16][K][D]   16777216
//   16912384 : float  Cpart8[16][K][D]   16777216
//   total ~34 MB (ws_size observed ~539 MB)

extern "C" void kernel_launch(void* const* d_in, const int* in_sizes, int n_in,
                              void* d_out, int out_size, void* d_ws, size_t ws_size,
                              hipStream_t stream) {
  const float* probs = (const float*)d_in[0];
  const float* a1 = (const float*)d_in[1];
  const float* a8 = (const float*)d_in[2];
  const float* m1 = (const float*)d_in[3];
  const float* m8 = (const float*)d_in[4];
  float* out = (float*)d_out;
  char* ws = (char*)d_ws;

  double* entpart = (double*)(ws + 0);
  int* labels = (int*)(ws + 32768);
  int* counts = (int*)(ws + 65536);
  float* sd1 = (float*)(ws + 65792);
  float* sd8 = (float*)(ws + 66048);
  float* msp1 = (float*)(ws + 66304);
  float* msp8 = (float*)(ws + 67328);
  float* w1 = (float*)(ws + 69632);
  float* w8 = (float*)(ws + 102400);
  float* Cpart1 = (float*)(ws + 135168);
  float* Cpart8 = (float*)(ws + 16912384);

  k_init<<<1, 256, 0, stream>>>(counts);
  k_labels<<<B_ / 4, 256, 0, stream>>>(probs, labels, counts);
  // per-tensor pairing: scatter re-reads the tensor k_norms just pulled into L3
  k_norms<<<B_, 256, 0, stream>>>(a1, labels, w1, sd1);
  k_scatter<<<CT_ * RS_, 256, 0, stream>>>(a1, labels, w1, Cpart1);
  k_norms<<<B_, 256, 0, stream>>>(a8, labels, w8, sd8);
  k_scatter<<<CT_ * RS_, 256, 0, stream>>>(a8, labels, w8, Cpart8);
  // masks last: don't disturb acts L3 residency
  k_entropy<<<ENT_GRID, 256, 0, stream>>>((const f32x4*)m1, (const f32x4*)m8, entpart);
  k_msm<<<512, 256, 0, stream>>>(Cpart1, Cpart8, msp1, msp8);
  k_final<<<1, 256, 0, stream>>>(entpart, counts, sd1, sd8, msp1, msp8, out);
}

// Round 13
// 250.731 us; speedup vs baseline: 2.0547x; 1.2526x over previous
//
#include <hip/hip_runtime.h>
#include <math.h>

#define B_ 8192
#define D_ 4096
#define K_ 64
#define EPSF 1e-8f
#define LN2F 0.69314718056f
#define ENT_GRID 2048
#define NSPLIT 8

typedef float f32x4 __attribute__((ext_vector_type(4)));

// ---------------- kernels ----------------

// zero counts[64] + sd1[64] + sd8[64] (contiguous 192 words)
__global__ void k_init(int* __restrict__ z) {
  if (threadIdx.x < 192) z[threadIdx.x] = 0;
}

// one wave per row; K_ == 64 == wavefront: one coalesced read + ballot
__global__ void k_labels(const float* __restrict__ probs, int* __restrict__ labels,
                         int* __restrict__ counts, int* __restrict__ rowlist) {
  int row = blockIdx.x * 4 + (threadIdx.x >> 6);
  int lane = threadIdx.x & 63;
  float p = probs[(size_t)row * K_ + lane];
  unsigned long long m = __ballot(p > 0.5f);
  if (lane == 0) {
    int k = __ffsll(m) - 1;
    labels[row] = (k >= 0) ? k : 0;
    if (k >= 0) {
      int pos = atomicAdd(&counts[k], 1);
      rowlist[k * B_ + pos] = row;
    }
  }
}

// block per row, sequential: w = 1/max(||a||,eps); ONE global atomic per block
// into sd[class] (proven ~6.4 TB/s shape). Also pulls the tensor into L3 for
// the k_fused classsum re-read.
__global__ __launch_bounds__(256) void k_norms(const float* __restrict__ acts,
                                               const int* __restrict__ labels,
                                               float* __restrict__ wout,
                                               float* __restrict__ sd) {
  __shared__ float lds[4];
  int row = blockIdx.x;
  const f32x4* rp = (const f32x4*)(acts + (size_t)row * D_);
  int t = threadIdx.x;
  f32x4 v0 = rp[t];
  f32x4 v1 = rp[t + 256];
  f32x4 v2 = rp[t + 512];
  f32x4 v3 = rp[t + 768];
  float s = v0.x * v0.x + v0.y * v0.y + v0.z * v0.z + v0.w * v0.w;
  s += v1.x * v1.x + v1.y * v1.y + v1.z * v1.z + v1.w * v1.w;
  s += v2.x * v2.x + v2.y * v2.y + v2.z * v2.z + v2.w * v2.w;
  s += v3.x * v3.x + v3.y * v3.y + v3.z * v3.z + v3.w * v3.w;
#pragma unroll
  for (int o = 32; o > 0; o >>= 1) s += __shfl_down(s, o);
  if ((t & 63) == 0) lds[t >> 6] = s;
  __syncthreads();
  if (t == 0) {
    s = lds[0] + lds[1] + lds[2] + lds[3];
    float w = 1.0f / fmaxf(sqrtf(s), EPSF);
    wout[row] = w;
    atomicAdd(&sd[labels[row]], s * w * w);
  }
}

__device__ __forceinline__ float ent1(float p) {
  p = fminf(fmaxf(p, EPSF), 1.0f - EPSF);
  float q = 1.0f - p;
  float lp = __builtin_amdgcn_logf(p);  // v_log_f32: log2
  float lq = __builtin_amdgcn_logf(fmaxf(q, 1e-38f));
  return -(p * lp + q * lq);
}

__device__ __forceinline__ float ent4(f32x4 v) {
  return ent1(v.x) + ent1(v.y) + ent1(v.z) + ent1(v.w);
}

// Fused: odd blocks stream mask entropy from HBM; even blocks gather the
// L3-resident acts tensor for the class sums. Equal 64KB work per block,
// 1:1 interleave -> the two memory supply paths (HBM vs L3) overlap.
__global__ __launch_bounds__(256) void k_fused(const float* __restrict__ acts,
                                               const f32x4* __restrict__ mask,
                                               const int* __restrict__ counts,
                                               const int* __restrict__ rowlist,
                                               const float* __restrict__ warr,
                                               float* __restrict__ Cpart,
                                               double* __restrict__ entp) {
  __shared__ float lds[8];
  int t = threadIdx.x;
  if (blockIdx.x & 1) {
    // ---- entropy on 64KB chunk (r8-proven ILP-8 body) ----
    int blk = blockIdx.x >> 1;              // 0..2047
    int base = blk * 4096;                  // f32x4 units
    float s1 = 0.f;
#pragma unroll
    for (int o = 0; o < 2; ++o) {
      f32x4 a[8];
#pragma unroll
      for (int j = 0; j < 8; ++j) a[j] = mask[base + t + (o * 8 + j) * 256];
#pragma unroll
      for (int j = 0; j < 8; ++j) s1 += ent4(a[j]);
    }
#pragma unroll
    for (int o = 32; o > 0; o >>= 1) s1 += __shfl_down(s1, o);
    if ((t & 63) == 0) lds[t >> 6] = s1;
    __syncthreads();
    if (t == 0) entp[blk] = (double)((lds[0] + lds[1] + lds[2] + lds[3]) * LN2F);
  } else {
    // ---- gather classsum (r3-proven shape), L3-hot ----
    int bid2 = blockIdx.x >> 1;  // 0..2047
    int k = bid2 & 63;
    int cc = (bid2 >> 6) & 3;
    int split = bid2 >> 8;  // 0..NSPLIT-1
    int cnt = counts[k];
    int beg = (cnt * split) / NSPLIT;
    int end = (cnt * (split + 1)) / NSPLIT;
    int col = cc * 1024 + 4 * t;
    const int* rl = rowlist + k * B_;
    f32x4 acc0 = 0.f, acc1 = 0.f, acc2 = 0.f, acc3 = 0.f;
    int r = beg;
    for (; r + 4 <= end; r += 4) {
      int row0 = rl[r], row1 = rl[r + 1], row2 = rl[r + 2], row3 = rl[r + 3];
      float w0 = warr[row0], w1 = warr[row1], w2 = warr[row2], w3 = warr[row3];
      f32x4 v0 = *(const f32x4*)(acts + (size_t)row0 * D_ + col);
      f32x4 v1 = *(const f32x4*)(acts + (size_t)row1 * D_ + col);
      f32x4 v2 = *(const f32x4*)(acts + (size_t)row2 * D_ + col);
      f32x4 v3 = *(const f32x4*)(acts + (size_t)row3 * D_ + col);
      acc0 += w0 * v0;
      acc1 += w1 * v1;
      acc2 += w2 * v2;
      acc3 += w3 * v3;
    }
    for (; r < end; ++r) {
      int row0 = rl[r];
      float w0 = warr[row0];
      f32x4 v0 = *(const f32x4*)(acts + (size_t)row0 * D_ + col);
      acc0 += w0 * v0;
    }
    acc0 += acc1 + acc2 + acc3;
    *(f32x4*)(Cpart + ((size_t)split * K_ + k) * D_ + col) = acc0;
  }
}

// mSm partials: 512 blocks; b<256 -> tensor1, else tensor8. k=b>>2, quarter q=b&3.
__global__ __launch_bounds__(256) void k_msm(const float* __restrict__ Cpart1,
                                             const float* __restrict__ Cpart8,
                                             float* __restrict__ msp1,
                                             float* __restrict__ msp8) {
  __shared__ float lds[4];
  int b = blockIdx.x;
  const float* Cpart = (b < 256) ? Cpart1 : Cpart8;
  float* msp = (b < 256) ? msp1 : msp8;
  b &= 255;
  int k = b >> 2;
  int q = b & 3;
  int t = threadIdx.x;
  int col = q * 1024 + 4 * t;
  f32x4 c = 0.f;
#pragma unroll
  for (int s = 0; s < NSPLIT; ++s)
    c += *(const f32x4*)(Cpart + ((size_t)s * K_ + k) * D_ + col);
  float sq = c.x * c.x + c.y * c.y + c.z * c.z + c.w * c.w;
#pragma unroll
  for (int o = 32; o > 0; o >>= 1) sq += __shfl_down(sq, o);
  if ((t & 63) == 0) lds[t >> 6] = sq;
  __syncthreads();
  if (t == 0) msp[blockIdx.x & 255] = lds[0] + lds[1] + lds[2] + lds[3];
}

// no LDS atomics: sd/counts precomputed by k_norms/k_labels
__global__ void k_final(const double* __restrict__ entpart, const int* __restrict__ counts,
                        const float* __restrict__ sd1, const float* __restrict__ sd8,
                        const float* __restrict__ msp1, const float* __restrict__ msp8,
                        float* __restrict__ out) {
  __shared__ double dl[8];
  int t = threadIdx.x;
  double e1 = 0.0, e8 = 0.0;
  for (int i = t; i < ENT_GRID; i += 256) {
    e1 += entpart[i];
    e8 += entpart[ENT_GRID + i];
  }
#pragma unroll
  for (int o = 32; o > 0; o >>= 1) {
    e1 += __shfl_down(e1, o);
    e8 += __shfl_down(e8, o);
  }
  int wid = t >> 6;
  if ((t & 63) == 0) { dl[wid] = e1; dl[4 + wid] = e8; }
  __syncthreads();
  float pcm1 = 0.f, pcm8 = 0.f, valid = 0.f;
  if (t < K_) {
    float mSm1 = msp1[t * 4] + msp1[t * 4 + 1] + msp1[t * 4 + 2] + msp1[t * 4 + 3];
    float mSm8 = msp8[t * 4] + msp8[t * 4 + 1] + msp8[t * 4 + 2] + msp8[t * 4 + 3];
    float n = (float)counts[t];
    bool v = (n >= 2.0f);
    float np = fmaxf(0.5f * n * (n - 1.0f), 1.0f);
    valid = v ? 1.0f : 0.f;
    pcm1 = v ? 0.5f * (mSm1 - sd1[t]) / np : 0.f;
    pcm8 = v ? 0.5f * (mSm8 - sd8[t]) / np : 0.f;
  }
#pragma unroll
  for (int o = 32; o > 0; o >>= 1) {
    pcm1 += __shfl_down(pcm1, o);
    pcm8 += __shfl_down(pcm8, o);
    valid += __shfl_down(valid, o);
  }
  if (t == 0) {
    double etot1 = dl[0] + dl[1] + dl[2] + dl[3];
    double etot8 = dl[4] + dl[5] + dl[6] + dl[7];
    float sp1 = (float)(etot1 / (double)((long long)B_ * D_));
    float sp8 = (float)(etot8 / (double)((long long)B_ * D_));
    float cs1 = (valid > 0.f) ? pcm1 / fmaxf(valid, 1.0f) : 0.f;
    float cs8 = (valid > 0.f) ? pcm8 / fmaxf(valid, 1.0f) : 0.f;
    float sim1 = -cs1, sim8 = -cs8;
    out[0] = sim1 + sim8 + 0.001f * (sp1 + sp8);
    out[1] = sim1;
    out[2] = sim8;
    out[3] = sp1;
    out[4] = sp8;
  }
}

// ---------------- launcher ----------------
// ws layout (bytes):
//   0        : double entpart[2][2048]   32768
//   32768    : int    labels[B]          32768
//   65536    : int    counts[64]         256  \
//   65792    : float  sd1[64]            256   } zeroed together (192 words)
//   66048    : float  sd8[64]            256  /
//   66304    : float  msp1[256]          1024
//   67328    : float  msp8[256]          1024
//   69632    : float  w1[B]              32768
//   102400   : float  w8[B]              32768
//   135168   : int    rowlist[K][B]      2097152
//   2232320  : float  Cpart1[8][K][D]    8388608
//   10620928 : float  Cpart8[8][K][D]    8388608
//   total ~19 MB (ws_size observed ~539 MB)

extern "C" void kernel_launch(void* const* d_in, const int* in_sizes, int n_in,
                              void* d_out, int out_size, void* d_ws, size_t ws_size,
                              hipStream_t stream) {
  const float* probs = (const float*)d_in[0];
  const float* a1 = (const float*)d_in[1];
  const float* a8 = (const float*)d_in[2];
  const float* m1 = (const float*)d_in[3];
  const float* m8 = (const float*)d_in[4];
  float* out = (float*)d_out;
  char* ws = (char*)d_ws;

  double* entpart = (double*)(ws + 0);
  int* labels = (int*)(ws + 32768);
  int* counts = (int*)(ws + 65536);
  float* sd1 = (float*)(ws + 65792);
  float* sd8 = (float*)(ws + 66048);
  float* msp1 = (float*)(ws + 66304);
  float* msp8 = (float*)(ws + 67328);
  float* w1 = (float*)(ws + 69632);
  float* w8 = (float*)(ws + 102400);
  int* rowlist = (int*)(ws + 135168);
  float* Cpart1 = (float*)(ws + 2232320);
  float* Cpart8 = (float*)(ws + 10620928);

  k_init<<<1, 256, 0, stream>>>(counts);
  k_labels<<<B_ / 4, 256, 0, stream>>>(probs, labels, counts, rowlist);
  // norms(aX) streams aX into L3; k_fused then overlaps the L3-hot classsum
  // gather with the HBM entropy stream of one mask
  k_norms<<<B_, 256, 0, stream>>>(a1, labels, w1, sd1);
  k_fused<<<4096, 256, 0, stream>>>(a1, (const f32x4*)m1, counts, rowlist, w1, Cpart1,
                                    entpart);
  k_norms<<<B_, 256, 0, stream>>>(a8, labels, w8, sd8);
  k_fused<<<4096, 256, 0, stream>>>(a8, (const f32x4*)m8, counts, rowlist, w8, Cpart8,
                                    entpart + ENT_GRID);
  k_msm<<<512, 256, 0, stream>>>(Cpart1, Cpart8, msp1, msp8);
  k_final<<<1, 256, 0, stream>>>(entpart, counts, sd1, sd8, msp1, msp8, out);
}

// Round 14
// 223.973 us; speedup vs baseline: 2.3002x; 1.1195x over previous
//
#include <hip/hip_runtime.h>
#include <math.h>

#define B_ 8192
#define D_ 4096
#define K_ 64
#define EPSF 1e-8f
#define LN2F 0.69314718056f
#define ENT_GRID 2048
#define SPLITS 32
#define GTASKS 4096   // 2 tensors x 64 classes x 32 splits
#define TTASKS 8192   // + 2 masks x 2048 chunks

typedef float f32x4 __attribute__((ext_vector_type(4)));

// ---------------- kernels ----------------

// zero counts[64] + sd1[64] + sd8[64] + ctr (256 contiguous words)
__global__ void k_init(int* __restrict__ z) { z[threadIdx.x] = 0; }

// one wave per row; K_ == 64 == wavefront: one coalesced read + ballot
__global__ void k_labels(const float* __restrict__ probs, int* __restrict__ counts,
                         int* __restrict__ rowlist) {
  int row = blockIdx.x * 4 + (threadIdx.x >> 6);
  int lane = threadIdx.x & 63;
  float p = probs[(size_t)row * K_ + lane];
  unsigned long long m = __ballot(p > 0.5f);
  if (lane == 0) {
    int k = __ffsll(m) - 1;
    if (k >= 0) {
      int pos = atomicAdd(&counts[k], 1);
      rowlist[k * B_ + pos] = row;
    }
  }
}

__device__ __forceinline__ float ent1(float p) {
  p = fminf(fmaxf(p, EPSF), 1.0f - EPSF);
  float q = 1.0f - p;
  float lp = __builtin_amdgcn_logf(p);  // v_log_f32: log2
  float lq = __builtin_amdgcn_logf(fmaxf(q, 1e-38f));
  return -(p * lp + q * lq);
}

__device__ __forceinline__ float ent4(f32x4 v) {
  return ent1(v.x) + ent1(v.y) + ent1(v.z) + ent1(v.w);
}

#define MLOADROW(V, ROW)                                                        \
  {                                                                             \
    const f32x4* rp_ = (const f32x4*)(a + (size_t)(ROW)*D_) + lane;             \
    _Pragma("unroll") for (int j = 0; j < 16; ++j) V[j] = rp_[64 * j];          \
  }

#define MCONSUME(V)                                                             \
  {                                                                             \
    float s_ = 0.f;                                                             \
    _Pragma("unroll") for (int j = 0; j < 16; ++j) s_ +=                        \
        V[j].x * V[j].x + V[j].y * V[j].y + V[j].z * V[j].z + V[j].w * V[j].w;  \
    _Pragma("unroll") for (int o = 32; o > 0; o >>= 1) s_ += __shfl_xor(s_, o); \
    float w_ = 1.0f / fmaxf(sqrtf(s_), EPSF);                                   \
    _Pragma("unroll") for (int j = 0; j < 16; ++j) acc[j] += w_ * V[j];         \
    sdacc += s_ * w_ * w_;                                                      \
  }

// Persistent mega-kernel, wave-level work stealing. Even tasks: r8's
// wave-per-row gather classnorm (latency/activate-limited, leaves BW idle).
// Odd tasks: 64KB sequential mask-entropy chunks (BW-limited, leaves latency
// slots idle). Dynamic grabbing self-balances the mix; the two traffic types
// overlap in the memory system.
__global__ __launch_bounds__(256) void k_mega(
    const float* __restrict__ a1, const float* __restrict__ a8,
    const f32x4* __restrict__ m1, const f32x4* __restrict__ m8,
    const int* __restrict__ counts, const int* __restrict__ rowlist,
    float* __restrict__ Cpart1, float* __restrict__ Cpart8, float* __restrict__ sd1,
    float* __restrict__ sd8, double* __restrict__ entpart, int* __restrict__ ctr) {
  int lane = threadIdx.x & 63;
  for (;;) {
    int task = 0;
    if (lane == 0) task = atomicAdd(ctr, 1);
    task = __shfl(task, 0);
    if (task >= TTASKS) break;
    int id = task >> 1;
    if (task & 1) {
      // ---- entropy: 64KB chunk; id: mask = id>>11, chunk = id&2047 ----
      const f32x4* base = ((id >> 11) ? m8 : m1) + (size_t)(id & 2047) * 4096;
      double* ep = entpart + ((id >> 11) ? ENT_GRID : 0);
      float s = 0.f;
      for (int o = 0; o < 8; ++o) {
        f32x4 v[8];
#pragma unroll
        for (int j = 0; j < 8; ++j) v[j] = base[lane + (o * 8 + j) * 64];
#pragma unroll
        for (int j = 0; j < 8; ++j) s += ent4(v[j]);
      }
#pragma unroll
      for (int o = 32; o > 0; o >>= 1) s += __shfl_xor(s, o);
      if (lane == 0) ep[id & 2047] = (double)(s * LN2F);
    } else {
      // ---- gather classnorm: id: tensor = id>>11, k = id&63, split = (id&2047)>>6 ----
      const float* a = (id >> 11) ? a8 : a1;
      float* Cpart = (id >> 11) ? Cpart8 : Cpart1;
      float* sd = (id >> 11) ? sd8 : sd1;
      int k = id & 63;
      int split = (id & 2047) >> 6;  // 0..31
      int cnt = counts[k];
      int beg = (cnt * split) / SPLITS;
      int end = (cnt * (split + 1)) / SPLITS;
      const int* rl = rowlist + k * B_;
      f32x4 acc[16];
#pragma unroll
      for (int j = 0; j < 16; ++j) acc[j] = 0.f;
      float sdacc = 0.f;
      f32x4 va[16], vb[16];
      int r = beg;
      if (end > beg) {
        MLOADROW(va, rl[r]);
        for (; r + 2 <= end; r += 2) {
          MLOADROW(vb, rl[r + 1]);
          MCONSUME(va);
          if (r + 2 < end) MLOADROW(va, rl[r + 2]);
          MCONSUME(vb);
        }
        if (r < end) MCONSUME(va);  // odd tail
      }
      float* cp = Cpart + ((size_t)split * K_ + k) * D_;
#pragma unroll
      for (int j = 0; j < 16; ++j) *(f32x4*)(cp + 4 * (lane + 64 * j)) = acc[j];
      if (lane == 0 && sdacc != 0.f) atomicAdd(&sd[k], sdacc);
    }
  }
}

// mSm partials: 512 blocks; b<256 -> tensor1, else tensor8. k=b>>2, quarter q=b&3.
__global__ __launch_bounds__(256) void k_msm(const float* __restrict__ Cpart1,
                                             const float* __restrict__ Cpart8,
                                             float* __restrict__ msp1,
                                             float* __restrict__ msp8) {
  __shared__ float lds[4];
  int b = blockIdx.x;
  const float* Cpart = (b < 256) ? Cpart1 : Cpart8;
  float* msp = (b < 256) ? msp1 : msp8;
  b &= 255;
  int k = b >> 2;
  int q = b & 3;
  int t = threadIdx.x;
  int col = q * 1024 + 4 * t;
  f32x4 c = 0.f;
  for (int s = 0; s < SPLITS; ++s)
    c += *(const f32x4*)(Cpart + ((size_t)s * K_ + k) * D_ + col);
  float sq = c.x * c.x + c.y * c.y + c.z * c.z + c.w * c.w;
#pragma unroll
  for (int o = 32; o > 0; o >>= 1) sq += __shfl_down(sq, o);
  if ((t & 63) == 0) lds[t >> 6] = sq;
  __syncthreads();
  if (t == 0) msp[blockIdx.x & 255] = lds[0] + lds[1] + lds[2] + lds[3];
}

__global__ void k_final(const double* __restrict__ entpart, const int* __restrict__ counts,
                        const float* __restrict__ sd1, const float* __restrict__ sd8,
                        const float* __restrict__ msp1, const float* __restrict__ msp8,
                        float* __restrict__ out) {
  __shared__ double dl[8];
  int t = threadIdx.x;
  double e1 = 0.0, e8 = 0.0;
  for (int i = t; i < ENT_GRID; i += 256) {
    e1 += entpart[i];
    e8 += entpart[ENT_GRID + i];
  }
#pragma unroll
  for (int o = 32; o > 0; o >>= 1) {
    e1 += __shfl_down(e1, o);
    e8 += __shfl_down(e8, o);
  }
  int wid = t >> 6;
  if ((t & 63) == 0) { dl[wid] = e1; dl[4 + wid] = e8; }
  __syncthreads();
  float pcm1 = 0.f, pcm8 = 0.f, valid = 0.f;
  if (t < K_) {
    float mSm1 = msp1[t * 4] + msp1[t * 4 + 1] + msp1[t * 4 + 2] + msp1[t * 4 + 3];
    float mSm8 = msp8[t * 4] + msp8[t * 4 + 1] + msp8[t * 4 + 2] + msp8[t * 4 + 3];
    float n = (float)counts[t];
    bool v = (n >= 2.0f);
    float np = fmaxf(0.5f * n * (n - 1.0f), 1.0f);
    valid = v ? 1.0f : 0.f;
    pcm1 = v ? 0.5f * (mSm1 - sd1[t]) / np : 0.f;
    pcm8 = v ? 0.5f * (mSm8 - sd8[t]) / np : 0.f;
  }
#pragma unroll
  for (int o = 32; o > 0; o >>= 1) {
    pcm1 += __shfl_down(pcm1, o);
    pcm8 += __shfl_down(pcm8, o);
    valid += __shfl_down(valid, o);
  }
  if (t == 0) {
    double etot1 = dl[0] + dl[1] + dl[2] + dl[3];
    double etot8 = dl[4] + dl[5] + dl[6] + dl[7];
    float sp1 = (float)(etot1 / (double)((long long)B_ * D_));
    float sp8 = (float)(etot8 / (double)((long long)B_ * D_));
    float cs1 = (valid > 0.f) ? pcm1 / fmaxf(valid, 1.0f) : 0.f;
    float cs8 = (valid > 0.f) ? pcm8 / fmaxf(valid, 1.0f) : 0.f;
    float sim1 = -cs1, sim8 = -cs8;
    out[0] = sim1 + sim8 + 0.001f * (sp1 + sp8);
    out[1] = sim1;
    out[2] = sim8;
    out[3] = sp1;
    out[4] = sp8;
  }
}

// ---------------- launcher ----------------
// ws layout (bytes):
//   0        : double entpart[2][2048]   32768
//   32768    : int    counts[64]         256  \
//   33024    : float  sd1[64]            256   \
//   33280    : float  sd8[64]            256    } zeroed together (256 words)
//   33536    : int    ctr + pad          256   /
//   33792    : float  msp1[256]          1024
//   34816    : float  msp8[256]          1024
//   65536    : int    rowlist[K][B]      2097152
//   2162688  : float  Cpart1[32][K][D]   33554432
//   35717120 : float  Cpart8[32][K][D]   33554432
//   total ~69 MB (ws_size observed ~539 MB)

extern "C" void kernel_launch(void* const* d_in, const int* in_sizes, int n_in,
                              void* d_out, int out_size, void* d_ws, size_t ws_size,
                              hipStream_t stream) {
  const float* probs = (const float*)d_in[0];
  const float* a1 = (const float*)d_in[1];
  const float* a8 = (const float*)d_in[2];
  const float* m1 = (const float*)d_in[3];
  const float* m8 = (const float*)d_in[4];
  float* out = (float*)d_out;
  char* ws = (char*)d_ws;

  double* entpart = (double*)(ws + 0);
  int* counts = (int*)(ws + 32768);
  float* sd1 = (float*)(ws + 33024);
  float* sd8 = (float*)(ws + 33280);
  int* ctr = (int*)(ws + 33536);
  float* msp1 = (float*)(ws + 33792);
  float* msp8 = (float*)(ws + 34816);
  int* rowlist = (int*)(ws + 65536);
  float* Cpart1 = (float*)(ws + 2162688);
  float* Cpart8 = (float*)(ws + 35717120);

  k_init<<<1, 256, 0, stream>>>(counts);
  k_labels<<<B_ / 4, 256, 0, stream>>>(probs, counts, rowlist);
  k_mega<<<768, 256, 0, stream>>>(a1, a8, (const f32x4*)m1, (const f32x4*)m8, counts,
                                  rowlist, Cpart1, Cpart8, sd1, sd8, entpart, ctr);
  k_msm<<<512, 256, 0, stream>>>(Cpart1, Cpart8, msp1, msp8);
  k_final<<<1, 256, 0, stream>>>(entpart, counts, sd1, sd8, msp1, msp8, out);
}

// Round 15
// 169.330 us; speedup vs baseline: 3.0424x; 1.3227x over previous
//
#include <hip/hip_runtime.h>
#include <math.h>

#define B_ 8192
#define D_ 4096
#define K_ 64
#define EPSF 1e-8f
#define LN2F 0.69314718056f
#define SPLITS 16   // gather splits per class per tensor
#define ECHUNKS 1024  // entropy chunks per mask (128KB each)

typedef float f32x4 __attribute__((ext_vector_type(4)));

// ---------------- kernels ----------------

// zero counts[64] + sd1[64] + sd8[64] (contiguous 192 words)
__global__ void k_init(int* __restrict__ z) {
  if (threadIdx.x < 192) z[threadIdx.x] = 0;
}

// one wave per row; K_ == 64 == wavefront: one coalesced read + ballot
__global__ void k_labels(const float* __restrict__ probs, int* __restrict__ counts,
                         int* __restrict__ rowlist) {
  int row = blockIdx.x * 4 + (threadIdx.x >> 6);
  int lane = threadIdx.x & 63;
  float p = probs[(size_t)row * K_ + lane];
  unsigned long long m = __ballot(p > 0.5f);
  if (lane == 0) {
    int k = __ffsll(m) - 1;
    if (k >= 0) {
      int pos = atomicAdd(&counts[k], 1);
      rowlist[k * B_ + pos] = row;
    }
  }
}

__device__ __forceinline__ float ent1(float p) {
  p = fminf(fmaxf(p, EPSF), 1.0f - EPSF);
  float q = 1.0f - p;
  float lp = __builtin_amdgcn_logf(p);  // v_log_f32: log2
  float lq = __builtin_amdgcn_logf(fmaxf(q, 1e-38f));
  return -(p * lp + q * lq);
}

__device__ __forceinline__ float ent4(f32x4 v) {
  return ent1(v.x) + ent1(v.y) + ent1(v.z) + ent1(v.w);
}

// Fused single-pass classnorm (r7 28-VGPR body) + mask entropy (r8 body).
// Even blocks: gather-classnorm — block per (tensor, class, split); per row the
// 4 waves each read a 1024-col quarter, LDS-combine ||a||^2 (parity buffer,
// one barrier), accumulate w*quarter in 4 f32x4 regs. ~8 rows x 16KB = 128KB.
// Odd blocks: entropy on one 128KB mask chunk, ILP-8 loads.
// Both bodies are low-VGPR -> co-compiled kernel keeps high occupancy, and the
// latency-limited gather traffic overlaps the BW-limited entropy stream.
__global__ __launch_bounds__(256) void k_fused(
    const float* __restrict__ a1, const float* __restrict__ a8,
    const f32x4* __restrict__ m1, const f32x4* __restrict__ m8,
    const int* __restrict__ counts, const int* __restrict__ rowlist,
    float* __restrict__ Cpart1, float* __restrict__ Cpart8, float* __restrict__ sd1,
    float* __restrict__ sd8, double* __restrict__ entpart) {
  __shared__ float sh[8];  // gather: lred[2][4]; entropy: partials[4]
  int t = threadIdx.x;
  if (blockIdx.x & 1) {
    // ---- entropy: one 128KB chunk of one mask ----
    int blk = blockIdx.x >> 1;  // 0..2047
    const f32x4* base = ((blk < ECHUNKS) ? m1 : m8) + (size_t)(blk & (ECHUNKS - 1)) * 8192;
    double* ep = entpart + ((blk < ECHUNKS) ? 0 : ECHUNKS);
    float s = 0.f;
#pragma unroll
    for (int o = 0; o < 4; ++o) {
      f32x4 v[8];
#pragma unroll
      for (int j = 0; j < 8; ++j) v[j] = base[t + (o * 8 + j) * 256];
#pragma unroll
      for (int j = 0; j < 8; ++j) s += ent4(v[j]);
    }
#pragma unroll
    for (int o = 32; o > 0; o >>= 1) s += __shfl_down(s, o);
    if ((t & 63) == 0) sh[t >> 6] = s;
    __syncthreads();
    if (t == 0) ep[blk & (ECHUNKS - 1)] = (double)((sh[0] + sh[1] + sh[2] + sh[3]) * LN2F);
  } else {
    // ---- gather classnorm ----
    int bid2 = blockIdx.x >> 1;  // 0..2047
    const float* a = (bid2 < 1024) ? a1 : a8;
    float* Cpart = (bid2 < 1024) ? Cpart1 : Cpart8;
    float* sd = (bid2 < 1024) ? sd1 : sd8;
    int b2 = bid2 & 1023;
    int k = b2 & 63;
    int split = b2 >> 6;  // 0..15
    int wave = t >> 6;
    int lane = t & 63;
    int cnt = counts[k];
    int beg = (cnt * split) / SPLITS;
    int end = (cnt * (split + 1)) / SPLITS;
    const int* rl = rowlist + k * B_;

    f32x4 acc0 = 0.f, acc1 = 0.f, acc2 = 0.f, acc3 = 0.f;
    float sdacc = 0.f;
    int par = 0;
    for (int r = beg; r < end; ++r, par ^= 1) {
      int row = rl[r];
      const f32x4* rp = (const f32x4*)(a + (size_t)row * D_) + (wave * 256 + lane);
      f32x4 v0 = rp[0];
      f32x4 v1 = rp[64];
      f32x4 v2 = rp[128];
      f32x4 v3 = rp[192];
      float s = v0.x * v0.x + v0.y * v0.y + v0.z * v0.z + v0.w * v0.w;
      s += v1.x * v1.x + v1.y * v1.y + v1.z * v1.z + v1.w * v1.w;
      s += v2.x * v2.x + v2.y * v2.y + v2.z * v2.z + v2.w * v2.w;
      s += v3.x * v3.x + v3.y * v3.y + v3.z * v3.z + v3.w * v3.w;
#pragma unroll
      for (int o = 32; o > 0; o >>= 1) s += __shfl_xor(s, o);
      if (lane == 0) sh[par * 4 + wave] = s;
      __syncthreads();
      float stot = sh[par * 4] + sh[par * 4 + 1] + sh[par * 4 + 2] + sh[par * 4 + 3];
      float w = 1.0f / fmaxf(sqrtf(stot), EPSF);
      acc0 += w * v0;
      acc1 += w * v1;
      acc2 += w * v2;
      acc3 += w * v3;
      sdacc += stot * w * w;
    }

    float* cp = Cpart + ((size_t)split * K_ + k) * D_ + wave * 1024;
    *(f32x4*)(cp + 4 * lane) = acc0;
    *(f32x4*)(cp + 4 * (64 + lane)) = acc1;
    *(f32x4*)(cp + 4 * (128 + lane)) = acc2;
    *(f32x4*)(cp + 4 * (192 + lane)) = acc3;
    if (t == 0 && sdacc != 0.f) atomicAdd(&sd[k], sdacc);
  }
}

// mSm partials: 512 blocks; b<256 -> tensor1, else tensor8. k=b>>2, quarter q=b&3.
__global__ __launch_bounds__(256) void k_msm(const float* __restrict__ Cpart1,
                                             const float* __restrict__ Cpart8,
                                             float* __restrict__ msp1,
                                             float* __restrict__ msp8) {
  __shared__ float lds[4];
  int b = blockIdx.x;
  const float* Cpart = (b < 256) ? Cpart1 : Cpart8;
  float* msp = (b < 256) ? msp1 : msp8;
  b &= 255;
  int k = b >> 2;
  int q = b & 3;
  int t = threadIdx.x;
  int col = q * 1024 + 4 * t;
  f32x4 c = 0.f;
#pragma unroll
  for (int s = 0; s < SPLITS; ++s)
    c += *(const f32x4*)(Cpart + ((size_t)s * K_ + k) * D_ + col);
  float sq = c.x * c.x + c.y * c.y + c.z * c.z + c.w * c.w;
#pragma unroll
  for (int o = 32; o > 0; o >>= 1) sq += __shfl_down(sq, o);
  if ((t & 63) == 0) lds[t >> 6] = sq;
  __syncthreads();
  if (t == 0) msp[blockIdx.x & 255] = lds[0] + lds[1] + lds[2] + lds[3];
}

__global__ void k_final(const double* __restrict__ entpart, const int* __restrict__ counts,
                        const float* __restrict__ sd1, const float* __restrict__ sd8,
                        const float* __restrict__ msp1, const float* __restrict__ msp8,
                        float* __restrict__ out) {
  __shared__ double dl[8];
  int t = threadIdx.x;
  double e1 = 0.0, e8 = 0.0;
  for (int i = t; i < ECHUNKS; i += 256) {
    e1 += entpart[i];
    e8 += entpart[ECHUNKS + i];
  }
#pragma unroll
  for (int o = 32; o > 0; o >>= 1) {
    e1 += __shfl_down(e1, o);
    e8 += __shfl_down(e8, o);
  }
  int wid = t >> 6;
  if ((t & 63) == 0) { dl[wid] = e1; dl[4 + wid] = e8; }
  __syncthreads();
  float pcm1 = 0.f, pcm8 = 0.f, valid = 0.f;
  if (t < K_) {
    float mSm1 = msp1[t * 4] + msp1[t * 4 + 1] + msp1[t * 4 + 2] + msp1[t * 4 + 3];
    float mSm8 = msp8[t * 4] + msp8[t * 4 + 1] + msp8[t * 4 + 2] + msp8[t * 4 + 3];
    float n = (float)counts[t];
    bool v = (n >= 2.0f);
    float np = fmaxf(0.5f * n * (n - 1.0f), 1.0f);
    valid = v ? 1.0f : 0.f;
    pcm1 = v ? 0.5f * (mSm1 - sd1[t]) / np : 0.f;
    pcm8 = v ? 0.5f * (mSm8 - sd8[t]) / np : 0.f;
  }
#pragma unroll
  for (int o = 32; o > 0; o >>= 1) {
    pcm1 += __shfl_down(pcm1, o);
    pcm8 += __shfl_down(pcm8, o);
    valid += __shfl_down(valid, o);
  }
  if (t == 0) {
    double etot1 = dl[0] + dl[1] + dl[2] + dl[3];
    double etot8 = dl[4] + dl[5] + dl[6] + dl[7];
    float sp1 = (float)(etot1 / (double)((long long)B_ * D_));
    float sp8 = (float)(etot8 / (double)((long long)B_ * D_));
    float cs1 = (valid > 0.f) ? pcm1 / fmaxf(valid, 1.0f) : 0.f;
    float cs8 = (valid > 0.f) ? pcm8 / fmaxf(valid, 1.0f) : 0.f;
    float sim1 = -cs1, sim8 = -cs8;
    out[0] = sim1 + sim8 + 0.001f * (sp1 + sp8);
    out[1] = sim1;
    out[2] = sim8;
    out[3] = sp1;
    out[4] = sp8;
  }
}

// ---------------- launcher ----------------
// ws layout (bytes):
//   0        : double entpart[2][1024]   16384
//   16384    : int    counts[64]         256  \
//   16640    : float  sd1[64]            256   } zeroed together (192 words)
//   16896    : float  sd8[64]            256  /
//   17152    : float  msp1[256]          1024
//   18176    : float  msp8[256]          1024
//   32768    : int    rowlist[K][B]      2097152
//   2129920  : float  Cpart1[16][K][D]   16777216
//   18907136 : float  Cpart8[16][K][D]   16777216
//   total ~35.7 MB (ws_size observed ~539 MB)

extern "C" void kernel_launch(void* const* d_in, const int* in_sizes, int n_in,
                              void* d_out, int out_size, void* d_ws, size_t ws_size,
                              hipStream_t stream) {
  const float* probs = (const float*)d_in[0];
  const float* a1 = (const float*)d_in[1];
  const float* a8 = (const float*)d_in[2];
  const float* m1 = (const float*)d_in[3];
  const float* m8 = (const float*)d_in[4];
  float* out = (float*)d_out;
  char* ws = (char*)d_ws;

  double* entpart = (double*)(ws + 0);
  int* counts = (int*)(ws + 16384);
  float* sd1 = (float*)(ws + 16640);
  float* sd8 = (float*)(ws + 16896);
  float* msp1 = (float*)(ws + 17152);
  float* msp8 = (float*)(ws + 18176);
  int* rowlist = (int*)(ws + 32768);
  float* Cpart1 = (float*)(ws + 2129920);
  float* Cpart8 = (float*)(ws + 18907136);

  k_init<<<1, 256, 0, stream>>>(counts);
  k_labels<<<B_ / 4, 256, 0, stream>>>(probs, counts, rowlist);
  // single fused pass: acts gather-classnorm (even blocks) overlapped with
  // mask entropy stream (odd blocks); minimum 536MB total traffic
  k_fused<<<4096, 256, 0, stream>>>(a1, a8, (const f32x4*)m1, (const f32x4*)m8, counts,
                                    rowlist, Cpart1, Cpart8, sd1, sd8, entpart);
  k_msm<<<512, 256, 0, stream>>>(Cpart1, Cpart8, msp1, msp8);
  k_final<<<1, 256, 0, stream>>>(entpart, counts, sd1, sd8, msp1, msp8, out);
}